// Round 5
// baseline (197.520 us; speedup 1.0000x reference)
//
#include <hip/hip_runtime.h>

#define NX   192
#define NXY  (NX * NX)
#define XG   48              // x-groups per row (4 outputs each)
#define YB   8               // y rows per block
#define ZC   6               // z outputs per block
#define NTH  (XG * YB)       // 384 threads = 6 waves
#define GY   (NX / YB)       // 24
#define GZ   (NX / ZC)       // 32
#define NBLK (GY * GZ)       // 768

static __device__ __forceinline__ float frcp(float x) {
#if __has_builtin(__builtin_amdgcn_rcpf)
    return __builtin_amdgcn_rcpf(x);
#else
    return 1.f / x;
#endif
}

// One z-slice of per-thread raw data: 3 y-rows x {float4 @x0, edge scalars
// @x0-1, @x0+4} x {pred, targ}. All named fields -> guaranteed registers.
struct Slice {
    float4 a0, a1, a2, b0, b1, b2;
    float am0, ap0, am1, ap1, am2, ap2;
    float bm0, bp0, bm1, bp1, bm2, bp2;
};

// accumulate one row's contribution to the 6 column stats (cols x0-1..x0+4)
#define ROWACC(a, b, am, ap, bm, bp)                                        \
    vI.x += a.x; vI.y += a.y; vI.z += a.z; vI.w += a.w;                     \
    vJ.x += b.x; vJ.y += b.y; vJ.z += b.z; vJ.w += b.w;                     \
    vII.x = fmaf(a.x, a.x, vII.x); vII.y = fmaf(a.y, a.y, vII.y);           \
    vII.z = fmaf(a.z, a.z, vII.z); vII.w = fmaf(a.w, a.w, vII.w);           \
    vJJ.x = fmaf(b.x, b.x, vJJ.x); vJJ.y = fmaf(b.y, b.y, vJJ.y);           \
    vJJ.z = fmaf(b.z, b.z, vJJ.z); vJJ.w = fmaf(b.w, b.w, vJJ.w);           \
    vIJ.x = fmaf(a.x, b.x, vIJ.x); vIJ.y = fmaf(a.y, b.y, vIJ.y);           \
    vIJ.z = fmaf(a.z, b.z, vIJ.z); vIJ.w = fmaf(a.w, b.w, vIJ.w);           \
    vIm += am; vIp += ap; vJm += bm; vJp += bp;                             \
    vIIm = fmaf(am, am, vIIm); vIIp = fmaf(ap, ap, vIIp);                   \
    vJJm = fmaf(bm, bm, vJJm); vJJp = fmaf(bp, bp, vJJp);                   \
    vIJm = fmaf(am, bm, vIJm); vIJp = fmaf(ap, bp, vIJp);

// x-window: output o = x0+o needs cols (x0+o-1, x0+o, x0+o+1)
#define WINM(n, v, m, p)                                                    \
    n.x = m   + v.x + v.y;                                                  \
    n.y = v.x + v.y + v.z;                                                  \
    n.z = v.y + v.z + v.w;                                                  \
    n.w = v.z + v.w + p;

#define NCCC(o)                                                             \
    {                                                                       \
        const float Is  = p0I.o  + p1I.o  + nI.o;                           \
        const float Js  = p0J.o  + p1J.o  + nJ.o;                           \
        const float IIs = p0II.o + p1II.o + nII.o;                          \
        const float JJs = p0JJ.o + p1JJ.o + nJJ.o;                          \
        const float IJs = p0IJ.o + p1IJ.o + nIJ.o;                          \
        const float uI = Is * inv27;                                        \
        const float uJ = Js * inv27;                                        \
        const float cross = fmaf(-uJ, Is, IJs);                             \
        const float Iv    = fmaf(-uI, Is, IIs);                             \
        const float Jv    = fmaf(-uJ, Js, JJs);                             \
        const float den   = fmaf(Iv, Jv, 1e-5f);                            \
        acc.o = fmaf(cross * cross, frcp(den), acc.o);                      \
    }

// Register-only LNCC with one-slice software pipelining: two Slice register
// buffers ping-pong; loads for slice z0+s are issued BEFORE computing stats
// on slice z0-1+s, so each load batch gets a full slice of compute (~450 cyc)
// to cover its L1/L2 latency. No LDS staging, no barriers in the hot loop.
__global__ __launch_bounds__(NTH, 3)
void lncc_main(const float* __restrict__ pred, const float* __restrict__ targ,
               double* __restrict__ partial) {
    __shared__ float wred[NTH / 64];

    const int k  = threadIdx.x;            // 0..47
    const int x0 = 4 * k;
    const int y  = blockIdx.y * YB + threadIdx.y;
    const int z0 = blockIdx.z * ZC;
    const bool okxm = (k > 0);
    const bool okxp = (k < XG - 1);
    const bool oky0 = (y > 0);
    const bool oky2 = (y < NX - 1);
    const int off0 = (y - 1) * NX + x0;
    const int off1 = y * NX + x0;
    const int off2 = (y + 1) * NX + x0;
    const float inv27 = 1.f / 27.f;
    const float4 zero4 = make_float4(0.f, 0.f, 0.f, 0.f);

    auto loadSlice = [&](int z, Slice& S) {
        S.a0 = S.a1 = S.a2 = zero4;
        S.b0 = S.b1 = S.b2 = zero4;
        S.am0 = S.ap0 = S.am1 = S.ap1 = S.am2 = S.ap2 = 0.f;
        S.bm0 = S.bp0 = S.bm1 = S.bp1 = S.bm2 = S.bp2 = 0.f;
        if ((unsigned)z < NX) {                           // wave-uniform
            const float* pz = pred + (size_t)z * NXY;
            const float* tz = targ + (size_t)z * NXY;
            if (oky0) {
                S.a0 = *(const float4*)(pz + off0);
                S.b0 = *(const float4*)(tz + off0);
                if (okxm) { S.am0 = pz[off0 - 1]; S.bm0 = tz[off0 - 1]; }
                if (okxp) { S.ap0 = pz[off0 + 4]; S.bp0 = tz[off0 + 4]; }
            }
            {
                S.a1 = *(const float4*)(pz + off1);
                S.b1 = *(const float4*)(tz + off1);
                if (okxm) { S.am1 = pz[off1 - 1]; S.bm1 = tz[off1 - 1]; }
                if (okxp) { S.ap1 = pz[off1 + 4]; S.bp1 = tz[off1 + 4]; }
            }
            if (oky2) {
                S.a2 = *(const float4*)(pz + off2);
                S.b2 = *(const float4*)(tz + off2);
                if (okxm) { S.am2 = pz[off2 - 1]; S.bm2 = tz[off2 - 1]; }
                if (okxp) { S.ap2 = pz[off2 + 4]; S.bp2 = tz[off2 + 4]; }
            }
        }
    };

    Slice Sa, Sb;
    loadSlice(z0 - 1, Sa);                 // slice consumed at s=0

    float4 p0I = zero4, p0J = zero4, p0II = zero4, p0JJ = zero4, p0IJ = zero4;
    float4 p1I = zero4, p1J = zero4, p1II = zero4, p1JJ = zero4, p1IJ = zero4;
    float4 acc = zero4;

#pragma unroll
    for (int s = 0; s < ZC + 2; ++s) {
        Slice& cur = (s & 1) ? Sb : Sa;
        Slice& nxt = (s & 1) ? Sa : Sb;
        if (s <= ZC) loadSlice(z0 + s, nxt);   // prefetch next slice NOW

        // ---- column stats for cur (slice z0-1+s): cols x0-1 .. x0+4 ----
        float4 vI = zero4, vJ = zero4, vII = zero4, vJJ = zero4, vIJ = zero4;
        float vIm = 0.f, vIp = 0.f, vJm = 0.f, vJp = 0.f;
        float vIIm = 0.f, vIIp = 0.f, vJJm = 0.f, vJJp = 0.f;
        float vIJm = 0.f, vIJp = 0.f;
        ROWACC(cur.a0, cur.b0, cur.am0, cur.ap0, cur.bm0, cur.bp0)
        ROWACC(cur.a1, cur.b1, cur.am1, cur.ap1, cur.bm1, cur.bp1)
        ROWACC(cur.a2, cur.b2, cur.am2, cur.ap2, cur.bm2, cur.bp2)

        // ---- x-window sums -> this slice's 2D sums (4 outputs) ----
        float4 nI, nJ, nII, nJJ, nIJ;
        WINM(nI,  vI,  vIm,  vIp)
        WINM(nJ,  vJ,  vJm,  vJp)
        WINM(nII, vII, vIIm, vIIp)
        WINM(nJJ, vJJ, vJJm, vJJp)
        WINM(nIJ, vIJ, vIJm, vIJp)

        // ---- emit output z0+s-2 once ring holds 3 slices ----
        if (s >= 2) {
            NCCC(x) NCCC(y) NCCC(z) NCCC(w)
        }
        p0I = p1I; p0J = p1J; p0II = p1II; p0JJ = p1JJ; p0IJ = p1IJ;
        p1I = nI;  p1J = nJ;  p1II = nII;  p1JJ = nJJ;  p1IJ = nIJ;
    }

    // ---- block reduction -> one double partial per block ----
    float v = acc.x + acc.y + acc.z + acc.w;
#pragma unroll
    for (int off = 32; off > 0; off >>= 1) v += __shfl_down(v, off);
    const int tid = threadIdx.y * XG + threadIdx.x;
    if ((tid & 63) == 0) wred[tid >> 6] = v;
    __syncthreads();
    if (tid == 0) {
        double t = 0.0;
#pragma unroll
        for (int i = 0; i < NTH / 64; ++i) t += (double)wred[i];
        partial[blockIdx.z * GY + blockIdx.y] = t;
    }
}

__global__ __launch_bounds__(256)
void lncc_reduce(const double* __restrict__ partial, float* __restrict__ out) {
    __shared__ double dred[4];
    double sum = 0.0;
    for (int i = threadIdx.x; i < NBLK; i += 256) sum += partial[i];
#pragma unroll
    for (int off = 32; off > 0; off >>= 1) sum += __shfl_down(sum, off);
    if ((threadIdx.x & 63) == 0) dred[threadIdx.x >> 6] = sum;
    __syncthreads();
    if (threadIdx.x == 0) {
        const double n = (double)NX * NX * NX;
        out[0] = (float)(-(dred[0] + dred[1] + dred[2] + dred[3]) / n);
    }
}

extern "C" void kernel_launch(void* const* d_in, const int* in_sizes, int n_in,
                              void* d_out, int out_size, void* d_ws, size_t ws_size,
                              hipStream_t stream) {
    const float* pred = (const float*)d_in[0];
    const float* targ = (const float*)d_in[1];
    double* partial = (double*)d_ws;
    float* out = (float*)d_out;

    dim3 grid(1, GY, GZ);                 // 1 x 24 x 32 = 768 blocks
    dim3 block(XG, YB);                   // 48 x 8 = 384 threads
    lncc_main<<<grid, block, 0, stream>>>(pred, targ, partial);
    lncc_reduce<<<1, 256, 0, stream>>>(partial, out);
}

// Round 6
// 130.114 us; speedup vs baseline: 1.5181x; 1.5181x over previous
//
#include <hip/hip_runtime.h>

#define NX   192
#define NXY  (NX * NX)
#define XG   48              // x-groups per row (4 outputs each)
#define YB   4               // y rows per block
#define ZC   6               // z outputs per block
#define NTH  (XG * YB)       // 192 threads = 3 waves
#define GY   (NX / YB)       // 48
#define GZ   (NX / ZC)       // 32
#define NBLK (GY * GZ)       // 1536

static __device__ __forceinline__ float frcp(float x) {
#if __has_builtin(__builtin_amdgcn_rcpf)
    return __builtin_amdgcn_rcpf(x);
#else
    return 1.f / x;
#endif
}

// ---- one z-slice of per-thread raw data, as FLAT NAMED variables only ----
// (twice-learned lesson: any address-taken local aggregate -> scratch spills)
#define DECL_SLICE(S)                                                        \
    float4 S##a0, S##a1, S##a2, S##b0, S##b1, S##b2;                         \
    float S##am0, S##ap0, S##am1, S##ap1, S##am2, S##ap2;                    \
    float S##bm0, S##bp0, S##bm1, S##bp1, S##bm2, S##bp2;

#define LOAD_SLICE(S, zz)                                                    \
    {                                                                        \
        const int z_ = (zz);                                                 \
        S##a0 = S##a1 = S##a2 = zero4;                                       \
        S##b0 = S##b1 = S##b2 = zero4;                                       \
        S##am0 = S##ap0 = S##am1 = S##ap1 = S##am2 = S##ap2 = 0.f;           \
        S##bm0 = S##bp0 = S##bm1 = S##bp1 = S##bm2 = S##bp2 = 0.f;           \
        if ((unsigned)z_ < NX) {                                             \
            const float* pz_ = pred + (size_t)z_ * NXY;                      \
            const float* tz_ = targ + (size_t)z_ * NXY;                      \
            if (oky0) {                                                      \
                S##a0 = *(const float4*)(pz_ + off0);                        \
                S##b0 = *(const float4*)(tz_ + off0);                        \
                if (okxm) { S##am0 = pz_[off0 - 1]; S##bm0 = tz_[off0 - 1]; }\
                if (okxp) { S##ap0 = pz_[off0 + 4]; S##bp0 = tz_[off0 + 4]; }\
            }                                                                \
            S##a1 = *(const float4*)(pz_ + off1);                            \
            S##b1 = *(const float4*)(tz_ + off1);                            \
            if (okxm) { S##am1 = pz_[off1 - 1]; S##bm1 = tz_[off1 - 1]; }    \
            if (okxp) { S##ap1 = pz_[off1 + 4]; S##bp1 = tz_[off1 + 4]; }    \
            if (oky2) {                                                      \
                S##a2 = *(const float4*)(pz_ + off2);                        \
                S##b2 = *(const float4*)(tz_ + off2);                        \
                if (okxm) { S##am2 = pz_[off2 - 1]; S##bm2 = tz_[off2 - 1]; }\
                if (okxp) { S##ap2 = pz_[off2 + 4]; S##bp2 = tz_[off2 + 4]; }\
            }                                                                \
        }                                                                    \
    }

// one row's contribution to the 6 column stats (cols x0-1 .. x0+4)
#define ROWACC(a, b, am, ap, bm, bp)                                         \
    vI.x += a.x; vI.y += a.y; vI.z += a.z; vI.w += a.w;                      \
    vJ.x += b.x; vJ.y += b.y; vJ.z += b.z; vJ.w += b.w;                      \
    vII.x = fmaf(a.x, a.x, vII.x); vII.y = fmaf(a.y, a.y, vII.y);            \
    vII.z = fmaf(a.z, a.z, vII.z); vII.w = fmaf(a.w, a.w, vII.w);            \
    vJJ.x = fmaf(b.x, b.x, vJJ.x); vJJ.y = fmaf(b.y, b.y, vJJ.y);            \
    vJJ.z = fmaf(b.z, b.z, vJJ.z); vJJ.w = fmaf(b.w, b.w, vJJ.w);            \
    vIJ.x = fmaf(a.x, b.x, vIJ.x); vIJ.y = fmaf(a.y, b.y, vIJ.y);            \
    vIJ.z = fmaf(a.z, b.z, vIJ.z); vIJ.w = fmaf(a.w, b.w, vIJ.w);            \
    vIm += am; vIp += ap; vJm += bm; vJp += bp;                              \
    vIIm = fmaf(am, am, vIIm); vIIp = fmaf(ap, ap, vIIp);                    \
    vJJm = fmaf(bm, bm, vJJm); vJJp = fmaf(bp, bp, vJJp);                    \
    vIJm = fmaf(am, bm, vIJm); vIJp = fmaf(ap, bp, vIJp);

// x-window: output o = x0+o needs cols (x0+o-1, x0+o, x0+o+1)
#define WINM(n, v, m, p)                                                     \
    n.x = m   + v.x + v.y;                                                   \
    n.y = v.x + v.y + v.z;                                                   \
    n.z = v.y + v.z + v.w;                                                   \
    n.w = v.z + v.w + p;

#define NCCC(o)                                                              \
    {                                                                        \
        const float Is  = p0I.o  + p1I.o  + nI.o;                            \
        const float Js  = p0J.o  + p1J.o  + nJ.o;                            \
        const float IIs = p0II.o + p1II.o + nII.o;                           \
        const float JJs = p0JJ.o + p1JJ.o + nJJ.o;                           \
        const float IJs = p0IJ.o + p1IJ.o + nIJ.o;                           \
        const float uI = Is * inv27;                                         \
        const float uJ = Js * inv27;                                         \
        const float cross = fmaf(-uJ, Is, IJs);                              \
        const float Iv    = fmaf(-uI, Is, IIs);                              \
        const float Jv    = fmaf(-uJ, Js, JJs);                              \
        const float den   = fmaf(Iv, Jv, 1e-5f);                             \
        acc.o = fmaf(cross * cross, frcp(den), acc.o);                       \
    }

// compute slice stats from S-named raw vars, window them, emit if EMIT, rotate ring
#define COMPUTE_SLICE(S, EMIT)                                               \
    {                                                                        \
        float4 vI = zero4, vJ = zero4, vII = zero4, vJJ = zero4, vIJ = zero4;\
        float vIm = 0.f, vIp = 0.f, vJm = 0.f, vJp = 0.f;                    \
        float vIIm = 0.f, vIIp = 0.f, vJJm = 0.f, vJJp = 0.f;                \
        float vIJm = 0.f, vIJp = 0.f;                                        \
        ROWACC(S##a0, S##b0, S##am0, S##ap0, S##bm0, S##bp0)                 \
        ROWACC(S##a1, S##b1, S##am1, S##ap1, S##bm1, S##bp1)                 \
        ROWACC(S##a2, S##b2, S##am2, S##ap2, S##bm2, S##bp2)                 \
        float4 nI, nJ, nII, nJJ, nIJ;                                        \
        WINM(nI,  vI,  vIm,  vIp)                                            \
        WINM(nJ,  vJ,  vJm,  vJp)                                            \
        WINM(nII, vII, vIIm, vIIp)                                           \
        WINM(nJJ, vJJ, vJJm, vJJp)                                           \
        WINM(nIJ, vIJ, vIJm, vIJp)                                           \
        if (EMIT) { NCCC(x) NCCC(y) NCCC(z) NCCC(w) }                        \
        p0I = p1I; p0J = p1J; p0II = p1II; p0JJ = p1JJ; p0IJ = p1IJ;         \
        p1I = nI;  p1J = nJ;  p1II = nII;  p1JJ = nJJ;  p1IJ = nIJ;          \
    }

// Register-only LNCC, software-pipelined one slice deep with NO aggregates:
// named A/B slice variables alternate as prefetch/compute targets across a
// manually unrolled 8-step schedule. Loads for slice z+1 issue before the
// stats of slice z are computed, so each load batch gets a full slice of
// compute to cover L2/L3 latency. No LDS, no barriers in the hot path.
__global__ __launch_bounds__(NTH)
void lncc_main(const float* __restrict__ pred, const float* __restrict__ targ,
               double* __restrict__ partial) {
    __shared__ float wred[NTH / 64];

    const int k  = threadIdx.x;            // 0..47
    const int x0 = 4 * k;
    const int y  = blockIdx.y * YB + threadIdx.y;
    const int z0 = blockIdx.z * ZC;
    const bool okxm = (k > 0);
    const bool okxp = (k < XG - 1);
    const bool oky0 = (y > 0);
    const bool oky2 = (y < NX - 1);
    const int off0 = (y - 1) * NX + x0;
    const int off1 = y * NX + x0;
    const int off2 = (y + 1) * NX + x0;
    const float inv27 = 1.f / 27.f;
    const float4 zero4 = make_float4(0.f, 0.f, 0.f, 0.f);

    DECL_SLICE(A)
    DECL_SLICE(B)

    float4 p0I = zero4, p0J = zero4, p0II = zero4, p0JJ = zero4, p0IJ = zero4;
    float4 p1I = zero4, p1J = zero4, p1II = zero4, p1JJ = zero4, p1IJ = zero4;
    float4 acc = zero4;

    LOAD_SLICE(A, z0 - 1)                          // consumed at step 0
    LOAD_SLICE(B, z0 + 0)  COMPUTE_SLICE(A, 0)     // step 0: slice z0-1
    LOAD_SLICE(A, z0 + 1)  COMPUTE_SLICE(B, 0)     // step 1: slice z0+0
    LOAD_SLICE(B, z0 + 2)  COMPUTE_SLICE(A, 1)     // step 2: emit z0+0
    LOAD_SLICE(A, z0 + 3)  COMPUTE_SLICE(B, 1)     // step 3: emit z0+1
    LOAD_SLICE(B, z0 + 4)  COMPUTE_SLICE(A, 1)     // step 4: emit z0+2
    LOAD_SLICE(A, z0 + 5)  COMPUTE_SLICE(B, 1)     // step 5: emit z0+3
    LOAD_SLICE(B, z0 + 6)  COMPUTE_SLICE(A, 1)     // step 6: emit z0+4
    COMPUTE_SLICE(B, 1)                            // step 7: emit z0+5

    // ---- block reduction -> one double partial per block ----
    float v = acc.x + acc.y + acc.z + acc.w;
#pragma unroll
    for (int off = 32; off > 0; off >>= 1) v += __shfl_down(v, off);
    const int tid = threadIdx.y * XG + threadIdx.x;
    if ((tid & 63) == 0) wred[tid >> 6] = v;
    __syncthreads();
    if (tid == 0) {
        double t = 0.0;
#pragma unroll
        for (int i = 0; i < NTH / 64; ++i) t += (double)wred[i];
        partial[blockIdx.z * GY + blockIdx.y] = t;
    }
}

__global__ __launch_bounds__(256)
void lncc_reduce(const double* __restrict__ partial, float* __restrict__ out) {
    __shared__ double dred[4];
    double sum = 0.0;
    for (int i = threadIdx.x; i < NBLK; i += 256) sum += partial[i];
#pragma unroll
    for (int off = 32; off > 0; off >>= 1) sum += __shfl_down(sum, off);
    if ((threadIdx.x & 63) == 0) dred[threadIdx.x >> 6] = sum;
    __syncthreads();
    if (threadIdx.x == 0) {
        const double n = (double)NX * NX * NX;
        out[0] = (float)(-(dred[0] + dred[1] + dred[2] + dred[3]) / n);
    }
}

extern "C" void kernel_launch(void* const* d_in, const int* in_sizes, int n_in,
                              void* d_out, int out_size, void* d_ws, size_t ws_size,
                              hipStream_t stream) {
    const float* pred = (const float*)d_in[0];
    const float* targ = (const float*)d_in[1];
    double* partial = (double*)d_ws;
    float* out = (float*)d_out;

    dim3 grid(1, GY, GZ);                 // 1 x 48 x 32 = 1536 blocks
    dim3 block(XG, YB);                   // 48 x 4 = 192 threads
    lncc_main<<<grid, block, 0, stream>>>(pred, targ, partial);
    lncc_reduce<<<1, 256, 0, stream>>>(partial, out);
}

// Round 7
// 122.303 us; speedup vs baseline: 1.6150x; 1.0639x over previous
//
#include <hip/hip_runtime.h>

#define NX   192
#define NXY  (NX * NX)
#define XG   48              // x-groups per row (4 outputs each)
#define YB   4               // y rows per block
#define ZC   4               // z outputs per block
#define NTH  (XG * YB)       // 192 threads = 3 waves
#define GY   (NX / YB)       // 48
#define GZ   (NX / ZC)       // 48
#define NBLK (GY * GZ)       // 2304

static __device__ __forceinline__ float frcp(float x) {
#if __has_builtin(__builtin_amdgcn_rcpf)
    return __builtin_amdgcn_rcpf(x);
#else
    return 1.f / x;
#endif
}

// x-window sums: col c = x0-1+c, cols 0..3 in v, cols 4,5 in s4,s5.
// output o needs cols o,o+1,o+2.
#define WIN(n, v, s4, s5)                    \
    n.x = v.x + v.y + v.z;                   \
    n.y = v.y + v.z + v.w;                   \
    n.z = v.z + v.w + s4;                    \
    n.w = v.w + s4 + s5;

#define NCCC(o)                                                            \
    {                                                                      \
        const float Is  = p0I.o  + p1I.o  + nI.o;                          \
        const float Js  = p0J.o  + p1J.o  + nJ.o;                          \
        const float IIs = p0II.o + p1II.o + nII.o;                         \
        const float JJs = p0JJ.o + p1JJ.o + nJJ.o;                         \
        const float IJs = p0IJ.o + p1IJ.o + nIJ.o;                         \
        const float uI = Is * inv27;                                       \
        const float uJ = Js * inv27;                                       \
        const float cross = fmaf(-uJ, Is, IJs);                            \
        const float Iv    = fmaf(-uI, Is, IIs);                            \
        const float Jv    = fmaf(-uJ, Js, JJs);                            \
        const float den   = fmaf(Iv, Jv, 1e-5f);                           \
        acc.o = fmaf(cross * cross, frcp(den), acc.o);                     \
    }

// Register-only LNCC: no LDS staging, no barriers, no per-wave pipelining.
// Round-4 structure (VGPR=64, spill-free) with 2.5x the wave supply:
// 2304 blocks x 3 waves = 27 waves/CU demand; latency hidden by TLP.
// (Round 6 A/B showed deep per-wave prefetch costs more in occupancy
// than it buys in ILP on this L3-resident workload.)
__global__ __launch_bounds__(NTH)
void lncc_main(const float* __restrict__ pred, const float* __restrict__ targ,
               double* __restrict__ partial) {
    __shared__ float wred[NTH / 64];

    const int k  = threadIdx.x;            // 0..47
    const int x0 = 4 * k;
    const int y  = blockIdx.y * YB + threadIdx.y;
    const int z0 = blockIdx.z * ZC;
    const bool okxm = (k > 0);
    const bool okxp = (k < XG - 1);
    const float inv27 = 1.f / 27.f;

    float4 zero4 = make_float4(0.f, 0.f, 0.f, 0.f);
    float4 p0I = zero4, p0J = zero4, p0II = zero4, p0JJ = zero4, p0IJ = zero4;
    float4 p1I = zero4, p1J = zero4, p1II = zero4, p1JJ = zero4, p1IJ = zero4;
    float4 acc = zero4;

    for (int s = 0; s < ZC + 2; ++s) {
        const int z = z0 - 1 + s;

        // ---- column stats for this slice: cols x0-1 .. x0+4 ----
        float4 vI = zero4, vJ = zero4, vII = zero4, vJJ = zero4, vIJ = zero4;
        float vI4 = 0.f, vI5 = 0.f, vJ4 = 0.f, vJ5 = 0.f;
        float vII4 = 0.f, vII5 = 0.f, vJJ4 = 0.f, vJJ5 = 0.f;
        float vIJ4 = 0.f, vIJ5 = 0.f;

        if ((unsigned)z < NX) {                       // wave-uniform
            const float* pz = pred + (size_t)z * NXY;
            const float* tz = targ + (size_t)z * NXY;
#pragma unroll
            for (int ry = 0; ry < 3; ++ry) {
                const int yy = y - 1 + ry;
                float4 qa = zero4, qb = zero4;
                float ea0 = 0.f, ea5 = 0.f, eb0 = 0.f, eb5 = 0.f;
                if ((unsigned)yy < NX) {
                    const float* ra = pz + yy * NX + x0;
                    const float* rb = tz + yy * NX + x0;
                    qa = *(const float4*)ra;
                    qb = *(const float4*)rb;
                    if (okxm) { ea0 = ra[-1]; eb0 = rb[-1]; }
                    if (okxp) { ea5 = ra[4];  eb5 = rb[4]; }
                }
                const float4 ra4 = make_float4(ea0, qa.x, qa.y, qa.z);
                const float4 rb4 = make_float4(eb0, qb.x, qb.y, qb.z);
                vI.x += ra4.x; vI.y += ra4.y; vI.z += ra4.z; vI.w += ra4.w;
                vJ.x += rb4.x; vJ.y += rb4.y; vJ.z += rb4.z; vJ.w += rb4.w;
                vII.x = fmaf(ra4.x, ra4.x, vII.x); vII.y = fmaf(ra4.y, ra4.y, vII.y);
                vII.z = fmaf(ra4.z, ra4.z, vII.z); vII.w = fmaf(ra4.w, ra4.w, vII.w);
                vJJ.x = fmaf(rb4.x, rb4.x, vJJ.x); vJJ.y = fmaf(rb4.y, rb4.y, vJJ.y);
                vJJ.z = fmaf(rb4.z, rb4.z, vJJ.z); vJJ.w = fmaf(rb4.w, rb4.w, vJJ.w);
                vIJ.x = fmaf(ra4.x, rb4.x, vIJ.x); vIJ.y = fmaf(ra4.y, rb4.y, vIJ.y);
                vIJ.z = fmaf(ra4.z, rb4.z, vIJ.z); vIJ.w = fmaf(ra4.w, rb4.w, vIJ.w);
                vI4 += qa.w;  vI5 += ea5;
                vJ4 += qb.w;  vJ5 += eb5;
                vII4 = fmaf(qa.w, qa.w, vII4);  vII5 = fmaf(ea5, ea5, vII5);
                vJJ4 = fmaf(qb.w, qb.w, vJJ4);  vJJ5 = fmaf(eb5, eb5, vJJ5);
                vIJ4 = fmaf(qa.w, qb.w, vIJ4);  vIJ5 = fmaf(ea5, eb5, vIJ5);
            }
        }

        // ---- x-window sums -> this slice's 2D sums (4 outputs) ----
        float4 nI, nJ, nII, nJJ, nIJ;
        WIN(nI,  vI,  vI4,  vI5)
        WIN(nJ,  vJ,  vJ4,  vJ5)
        WIN(nII, vII, vII4, vII5)
        WIN(nJJ, vJJ, vJJ4, vJJ5)
        WIN(nIJ, vIJ, vIJ4, vIJ5)

        // ---- emit output z-1 once ring holds z-2,z-1,z ----
        if (s >= 2) {
            NCCC(x) NCCC(y) NCCC(z) NCCC(w)
        }
        p0I = p1I; p0J = p1J; p0II = p1II; p0JJ = p1JJ; p0IJ = p1IJ;
        p1I = nI;  p1J = nJ;  p1II = nII;  p1JJ = nJJ;  p1IJ = nIJ;
    }

    // ---- block reduction -> one double partial per block ----
    float v = acc.x + acc.y + acc.z + acc.w;
#pragma unroll
    for (int off = 32; off > 0; off >>= 1) v += __shfl_down(v, off);
    const int tid = threadIdx.y * XG + threadIdx.x;
    if ((tid & 63) == 0) wred[tid >> 6] = v;
    __syncthreads();
    if (tid == 0) {
        double t = 0.0;
#pragma unroll
        for (int i = 0; i < NTH / 64; ++i) t += (double)wred[i];
        partial[blockIdx.z * GY + blockIdx.y] = t;
    }
}

__global__ __launch_bounds__(256)
void lncc_reduce(const double* __restrict__ partial, float* __restrict__ out) {
    __shared__ double dred[4];
    double sum = 0.0;
    for (int i = threadIdx.x; i < NBLK; i += 256) sum += partial[i];
#pragma unroll
    for (int off = 32; off > 0; off >>= 1) sum += __shfl_down(sum, off);
    if ((threadIdx.x & 63) == 0) dred[threadIdx.x >> 6] = sum;
    __syncthreads();
    if (threadIdx.x == 0) {
        const double n = (double)NX * NX * NX;
        out[0] = (float)(-(dred[0] + dred[1] + dred[2] + dred[3]) / n);
    }
}

extern "C" void kernel_launch(void* const* d_in, const int* in_sizes, int n_in,
                              void* d_out, int out_size, void* d_ws, size_t ws_size,
                              hipStream_t stream) {
    const float* pred = (const float*)d_in[0];
    const float* targ = (const float*)d_in[1];
    double* partial = (double*)d_ws;
    float* out = (float*)d_out;

    dim3 grid(1, GY, GZ);                 // 1 x 48 x 48 = 2304 blocks
    dim3 block(XG, YB);                   // 48 x 4 = 192 threads
    lncc_main<<<grid, block, 0, stream>>>(pred, targ, partial);
    lncc_reduce<<<1, 256, 0, stream>>>(partial, out);
}